// Round 16
// baseline (133.040 us; speedup 1.0000x reference)
//
#include <hip/hip_runtime.h>
#include <hip/hip_bf16.h>

typedef unsigned int uint32;
typedef unsigned short ushort_t;

typedef __bf16 bf16x8 __attribute__((ext_vector_type(8)));
typedef float f32x4 __attribute__((ext_vector_type(4)));

__device__ __forceinline__ ushort_t f2bf(float f) {
    uint32 u = __float_as_uint(f);
    u += 0x7fffu + ((u >> 16) & 1u);
    return (ushort_t)(u >> 16);
}
__device__ __forceinline__ float bf2f(ushort_t h) {
    return __uint_as_float(((uint32)h) << 16);
}

union U16 { int4 v; ushort_t u[8]; };
union UB8 { bf16x8 v; ushort_t u[8]; };

// async global->LDS, 16B per lane (dest = wave-uniform base + lane*16)
__device__ __forceinline__ void gll16(const ushort_t* g, ushort_t* l) {
    __builtin_amdgcn_global_load_lds(
        (const __attribute__((address_space(1))) unsigned int*)g,
        (__attribute__((address_space(3))) unsigned int*)l, 16, 0, 0);
}

#define SBAR() __builtin_amdgcn_s_barrier()
#define VM0()  asm volatile("s_waitcnt vmcnt(0)" ::: "memory")
#define VM2()  asm volatile("s_waitcnt vmcnt(2)" ::: "memory")
#define VM4()  asm volatile("s_waitcnt vmcnt(4)" ::: "memory")

// swizzled LDS fragment offset (BK=32): row r, kk in {0,8,16,24}
__device__ __forceinline__ int frag3(int r, int kk) {
    return r * 32 + ((((kk >> 3) ^ ((r >> 1) & 3))) << 3);
}

// ===========================================================================
// 256x256 GEMM bf16, BK=32, 1024 thr = 16 waves, 3-ring 96KB.
// Deep prefetch: stage A,B of tile t+2 during tile t; boundary vmcnt(2).
// ===========================================================================
template<int NT>
__device__ __forceinline__ void gemm256_bk32(
    const ushort_t* __restrict__ A, int lda,
    const ushort_t* __restrict__ B, int ldb,
    ushort_t* lds, f32x4 acc[4][4])
{
    const int tid = threadIdx.x;
    const int lane = tid & 63, wid = tid >> 6;
    const int wm = wid >> 2, wn = wid & 3;
    const int l15 = lane & 15, kk = (lane >> 4) * 8;
    const int srow = tid >> 2;
    const int sc4 = (tid & 3) ^ ((tid >> 3) & 3);   // inverse swizzle on src

    #define STAGE3(G, ldg, X, op)                                            \
        gll16(&(G)[(size_t)srow * (ldg) + (X) * 32 + sc4 * 8],               \
              &lds[(((X) % 3) * 2 + (op)) * 8192 + tid * 8])

    STAGE3(A, lda, 0, 0);
    STAGE3(B, ldb, 0, 1);
    if (NT > 1) { STAGE3(A, lda, 1, 0); STAGE3(B, ldb, 1, 1); VM2(); }
    else VM0();
    SBAR();

    for (int t = 0; t < NT; ++t) {
        const ushort_t* Ab = lds + (t % 3) * 16384;
        const ushort_t* Bb = Ab + 8192;
        if (t + 2 < NT) { STAGE3(A, lda, t + 2, 0); STAGE3(B, ldb, t + 2, 1); }
        bf16x8 af[4], bfr[4];
#pragma unroll
        for (int m = 0; m < 4; ++m)
            af[m] = *(const bf16x8*)&Ab[frag3(wm * 64 + m * 16 + l15, kk)];
#pragma unroll
        for (int n = 0; n < 4; ++n)
            bfr[n] = *(const bf16x8*)&Bb[frag3(wn * 64 + n * 16 + l15, kk)];
#pragma unroll
        for (int m = 0; m < 4; ++m)
#pragma unroll
            for (int n = 0; n < 4; ++n)
                acc[m][n] = __builtin_amdgcn_mfma_f32_16x16x32_bf16(
                    af[m], bfr[n], acc[m][n], 0, 0, 0);
        if (t + 1 < NT) {
            if (t + 2 < NT) VM2(); else VM0();
            SBAR();
        }
    }
    #undef STAGE3
}

// ===========================================================================
// 128x128 GEMM bf16, BK=32, 256 thr = 4 waves, RING-4 (64KB, 2 blocks/CU).
// Stage A,B of t+2 during t; boundary vmcnt(4).
// ===========================================================================
__device__ __forceinline__ void gemm128_bk32(
    const ushort_t* __restrict__ A, int lda,
    const ushort_t* __restrict__ B, int ldb,
    ushort_t* lds, int NT, f32x4 acc[4][4])
{
    const int tid = threadIdx.x;
    const int lane = tid & 63, wid = tid >> 6;
    const int wm = wid >> 1, wn = wid & 1;
    const int l15 = lane & 15, kk = (lane >> 4) * 8;

    #define STG128(G, ldg, X, op) do {                                       \
        _Pragma("unroll")                                                    \
        for (int i = 0; i < 2; ++i) {                                        \
            int c = i * 256 + tid;                                           \
            int row = c >> 2;                                                \
            int slot = (c & 3) ^ ((row >> 1) & 3);                           \
            gll16(&(G)[(size_t)row * (ldg) + (X) * 32 + slot * 8],           \
                  &lds[(((X) % 4) * 2 + (op)) * 4096 + c * 8]);              \
        } } while (0)

    STG128(A, lda, 0, 0);
    STG128(B, ldb, 0, 1);
    if (NT > 1) { STG128(A, lda, 1, 0); STG128(B, ldb, 1, 1); VM4(); }
    else VM0();
    SBAR();

    for (int t = 0; t < NT; ++t) {
        const ushort_t* Ab = lds + (t % 4) * 8192;
        const ushort_t* Bb = Ab + 4096;
        if (t + 2 < NT) { STG128(A, lda, t + 2, 0); STG128(B, ldb, t + 2, 1); }
        bf16x8 af[4], bfr[4];
#pragma unroll
        for (int m = 0; m < 4; ++m)
            af[m] = *(const bf16x8*)&Ab[frag3(wm * 64 + m * 16 + l15, kk)];
#pragma unroll
        for (int n = 0; n < 4; ++n)
            bfr[n] = *(const bf16x8*)&Bb[frag3(wn * 64 + n * 16 + l15, kk)];
#pragma unroll
        for (int m = 0; m < 4; ++m)
#pragma unroll
            for (int n = 0; n < 4; ++n)
                acc[m][n] = __builtin_amdgcn_mfma_f32_16x16x32_bf16(
                    af[m], bfr[n], acc[m][n], 0, 0, 0);
        if (t + 1 < NT) {
            if (t + 2 < NT) VM4(); else VM0();
            SBAR();
        }
    }
    #undef STG128
}

// ---------------------------------------------------------------------------
// Kernel 0 (merged): fp32->bf16 copies (X, Wv->Bmat rows 1024..2047) +
// transpose-convert Wq,Wk -> WqT,WkT.
// ---------------------------------------------------------------------------
__global__ __launch_bounds__(256) void conv_all(
    const float* __restrict__ X,  const float* __restrict__ Wq,
    const float* __restrict__ Wk, const float* __restrict__ Wv,
    ushort_t* __restrict__ Xb, ushort_t* __restrict__ BmatV,
    ushort_t* __restrict__ WqT, ushort_t* __restrict__ WkT)
{
    __shared__ ushort_t ts[64][72];
    const int gb = blockIdx.x;
    const int tid = threadIdx.x;
    if (gb < 4608) {
        const float* src;
        ushort_t* dst;
        if (gb < 4096) {
            size_t base = ((size_t)gb * 256 + tid) * 8;
            src = X + base; dst = Xb + base;
        } else {
            size_t base = ((size_t)(gb - 4096) * 256 + tid) * 8;
            src = Wv + base; dst = BmatV + base;
        }
        float4 f0 = *(const float4*)src;
        float4 f1 = *(const float4*)(src + 4);
        U16 o;
        o.u[0] = f2bf(f0.x); o.u[1] = f2bf(f0.y); o.u[2] = f2bf(f0.z); o.u[3] = f2bf(f0.w);
        o.u[4] = f2bf(f1.x); o.u[5] = f2bf(f1.y); o.u[6] = f2bf(f1.z); o.u[7] = f2bf(f1.w);
        *(int4*)dst = o.v;
        return;
    }
    // ---- transpose path
    const int t2 = gb - 4608;            // [0,512)
    const int z = t2 >> 8;
    const int bx = t2 & 15, by = (t2 >> 4) & 15;
    const float* W = z ? Wk : Wq;
    ushort_t* Dt = z ? WkT : WqT;
    const int o0 = bx * 64, d0 = by * 64;
    const int row = tid >> 2, q = tid & 3;
#pragma unroll
    for (int c4 = 0; c4 < 4; ++c4) {
        float4 f = *(const float4*)&W[(size_t)(o0 + row) * 1024 + d0 + q * 16 + c4 * 4];
        ts[row][q * 16 + c4 * 4 + 0] = f2bf(f.x);
        ts[row][q * 16 + c4 * 4 + 1] = f2bf(f.y);
        ts[row][q * 16 + c4 * 4 + 2] = f2bf(f.z);
        ts[row][q * 16 + c4 * 4 + 3] = f2bf(f.w);
    }
    __syncthreads();
#pragma unroll
    for (int i = 0; i < 2; ++i) {
        int c = tid + 256 * i;
        int drow = c >> 3, ocol8 = c & 7;
        U16 vv;
#pragma unroll
        for (int j = 0; j < 8; ++j) vv.u[j] = ts[ocol8 * 8 + j][drow];
        *(int4*)&Dt[(size_t)(d0 + drow) * 1024 + o0 + ocol8 * 8] = vv.v;
    }
}

// ---------------------------------------------------------------------------
// Kernel 0c: Mt GEMM: Bmat[a][d] = sum_o WkT[a][o]*WqT[d][o]. grid (8,8).
// ---------------------------------------------------------------------------
__global__ __launch_bounds__(256) void mt_gemm(
    const ushort_t* __restrict__ WkT, const ushort_t* __restrict__ WqT,
    ushort_t* __restrict__ Bmat)
{
    __shared__ __align__(16) ushort_t lds[32768];  // 64 KB (ring-4)
    const int bm = blockIdx.y, bn = blockIdx.x;
    const int tid = threadIdx.x;
    f32x4 acc[4][4] = {};
    gemm128_bk32(WkT + (size_t)bm * 128 * 1024, 1024,
                 WqT + (size_t)bn * 128 * 1024, 1024, lds, 32, acc);
    ushort_t* Dst = Bmat + (size_t)bm * 128 * 1024 + bn * 128;
    const int lane = tid & 63, wid = tid >> 6;
    const int wr = wid >> 1, wc = wid & 1;
#pragma unroll
    for (int m = 0; m < 4; ++m)
#pragma unroll
        for (int n = 0; n < 4; ++n)
#pragma unroll
            for (int j = 0; j < 4; ++j) {
                int row = wr * 64 + m * 16 + (lane >> 4) * 4 + j;
                int col = wc * 64 + n * 16 + (lane & 15);
                Dst[(size_t)row * 1024 + col] = f2bf(acc[m][n][j]);
            }
}

// ---------------------------------------------------------------------------
// Kernel 1: T1|V projection. 1-D grid 256, XCD-swizzled. 1024 thr.
// ---------------------------------------------------------------------------
__global__ __launch_bounds__(1024) void t1v_gemm256(
    const ushort_t* __restrict__ Xb, const ushort_t* __restrict__ Bmat,
    ushort_t* __restrict__ T1, ushort_t* __restrict__ V)
{
    __shared__ __align__(16) ushort_t lds[49152];  // 96 KB
    const int id = blockIdx.x;            // [0,256)
    const int xcd = id & 7, l = id >> 3;  // l in [0,32)
    const int bm = xcd * 4 + (l >> 3);    // [0,32)
    const int bn = l & 7;                 // [0,8)
    f32x4 acc[4][4] = {};
    gemm256_bk32<32>(Xb + (size_t)bm * 256 * 1024, 1024,
                     Bmat + (size_t)bn * 256 * 1024, 1024, lds, acc);
    ushort_t* Dst = ((bn < 4) ? T1 : V)
                  + (size_t)bm * 256 * 1024 + (bn & 3) * 256;
    const int tid = threadIdx.x, lane = tid & 63, wid = tid >> 6;
    const int wm = wid >> 2, wn = wid & 3;
#pragma unroll
    for (int m = 0; m < 4; ++m)
#pragma unroll
        for (int n = 0; n < 4; ++n)
#pragma unroll
            for (int j = 0; j < 4; ++j) {
                int row = wm * 64 + m * 16 + (lane >> 4) * 4 + j;
                int col = wn * 64 + n * 16 + (lane & 15);
                Dst[(size_t)row * 1024 + col] = f2bf(acc[m][n][j]);
            }
}

// ---------------------------------------------------------------------------
// Kernel 2: P = exp((T1 @ X^T)/32) bf16, causal-masked (exact 0), 256^2;
// masked blocks transpose V. 1-D grid 256, XCD-swizzled.
// ---------------------------------------------------------------------------
__global__ __launch_bounds__(1024) void scores_gemm256(
    const ushort_t* __restrict__ T1, const ushort_t* __restrict__ Xb,
    ushort_t* __restrict__ P,
    const ushort_t* __restrict__ V, ushort_t* __restrict__ Vt)
{
    __shared__ __align__(16) ushort_t lds[49152];
    const int id = blockIdx.x;            // [0,256)
    const int xcd = id & 7, l = id >> 3;  // l in [0,32)
    const int b = xcd >> 1, h = xcd & 1;
    const int bm = 4 * h + (l >> 3);      // [0,8)
    const int bn = l & 7;                 // [0,8)
    const int tid = threadIdx.x;
    if (bn > bm) {
        // ---- V-transpose duty: 512 64x64 tiles/batch over 28 masked blocks
        ushort_t (*ts)[72] = (ushort_t(*)[72])lds;
        const ushort_t* Vb = V + (size_t)b * 2048 * 1024;
        ushort_t* Vtb = Vt + (size_t)b * 1024 * 2048;
        const int rank = bn * (bn - 1) / 2 + bm;   // [0,28)
        for (int t = rank; t < 512; t += 28) {
            int k0 = (t >> 4) * 64, d0 = (t & 15) * 64;
            __syncthreads();
            if (tid < 512) {
                int row = tid >> 3, col8 = tid & 7;
                U16 vv;
                vv.v = *(const int4*)&Vb[(size_t)(k0 + row) * 1024 + d0 + col8 * 8];
#pragma unroll
                for (int j = 0; j < 8; ++j) ts[row][col8 * 8 + j] = vv.u[j];
            }
            __syncthreads();
            if (tid < 512) {
                int drow = tid >> 3, kcol8 = tid & 7;
                U16 vv;
#pragma unroll
                for (int j = 0; j < 8; ++j) vv.u[j] = ts[kcol8 * 8 + j][drow];
                *(int4*)&Vtb[(size_t)(d0 + drow) * 2048 + k0 + kcol8 * 8] = vv.v;
            }
        }
        return;
    }
    f32x4 acc[4][4] = {};
    gemm256_bk32<32>(T1 + (size_t)b * 2048 * 1024 + (size_t)bm * 256 * 1024, 1024,
                     Xb + (size_t)b * 2048 * 1024 + (size_t)bn * 256 * 1024, 1024,
                     lds, acc);
    ushort_t* Pb = P + (size_t)b * 2048 * 2048 + (size_t)bm * 256 * 2048 + bn * 256;
    const int lane = tid & 63, wid = tid >> 6;
    const int wm = wid >> 2, wn = wid & 3;
    const bool diag = (bn == bm);
#pragma unroll
    for (int m = 0; m < 4; ++m)
#pragma unroll
        for (int n = 0; n < 4; ++n)
#pragma unroll
            for (int j = 0; j < 4; ++j) {
                int row = wm * 64 + m * 16 + (lane >> 4) * 4 + j;
                int col = wn * 64 + n * 16 + (lane & 15);
                float p = __expf(fminf(acc[m][n][j] * 0.03125f, 30.f));
                if (diag && col > row) p = 0.f;   // causal: exact 0
                Pb[(size_t)row * 2048 + col] = f2bf(p);
            }
}

// ---------------------------------------------------------------------------
// Kernel 3: pv_fused = P@V + rowsum normalize (P pre-exp'd, pre-masked).
// RING-4 deep prefetch (R15). NEW (R16): XCD-grouped mapping so the 8
// bn-blocks sharing one P strip land on ONE XCD (L2-resident, 8x reuse):
//   x = L&7 (XCD under round-robin), j = L>>3; round = j>>5 picks
//   bm = x (round 1) or 15-x (round 2); r = j&31: b = r&3, bn = r>>2.
// Bijective; per-CU work = (x+1)+(16-x) = 17 strips (balance preserved);
// per XCD-round live P = 4 strips x (bm+1)*32KB <= 2MB -> fits 4MB L2.
// ---------------------------------------------------------------------------
__global__ __launch_bounds__(256) void pv_fused(
    const ushort_t* __restrict__ S, const ushort_t* __restrict__ Vt,
    float* __restrict__ O)
{
    __shared__ __align__(16) ushort_t lds[32768];  // 64 KB (ring-4)
    const int L = blockIdx.x;   // [0,512)
    const int x = L & 7, j = L >> 3;
    const int r = j & 31;
    const int bm = (j >> 5) ? (15 - x) : x;
    const int b = r & 3;
    const int bn = r >> 2;
    const int tid = threadIdx.x;
    const int lane = tid & 63, wid = tid >> 6;
    const int wm = wid >> 1, wn = wid & 1;
    const int l15 = lane & 15, kk = (lane >> 4) * 8;
    const ushort_t* A = S + (size_t)b * 2048 * 2048 + (size_t)bm * 128 * 2048;
    const ushort_t* Bm = Vt + (size_t)b * 1024 * 2048 + (size_t)bn * 128 * 2048;
    const int NT = (bm + 1) * 4;

    f32x4 acc[4][4] = {};
    float lsum[4] = {0.f, 0.f, 0.f, 0.f};

    #define STGF(G, ldg, X, op) do {                                         \
        _Pragma("unroll")                                                    \
        for (int i = 0; i < 2; ++i) {                                        \
            int c = i * 256 + tid;                                           \
            int row = c >> 2;                                                \
            int slot = (c & 3) ^ ((row >> 1) & 3);                           \
            gll16(&(G)[(size_t)row * (ldg) + (X) * 32 + slot * 8],           \
                  &lds[(((X) % 4) * 2 + (op)) * 4096 + c * 8]);              \
        } } while (0)

    STGF(A, 2048, 0, 0);
    STGF(Bm, 2048, 0, 1);
    if (NT > 1) { STGF(A, 2048, 1, 0); STGF(Bm, 2048, 1, 1); VM4(); }
    else VM0();
    SBAR();

    for (int t = 0; t < NT; ++t) {
        const ushort_t* Ab = lds + (t % 4) * 8192;
        const ushort_t* Bb = Ab + 4096;
        if (t + 2 < NT) { STGF(A, 2048, t + 2, 0); STGF(Bm, 2048, t + 2, 1); }
        UB8 af[4];
        bf16x8 bfr[4];
#pragma unroll
        for (int m = 0; m < 4; ++m)
            af[m].v = *(const bf16x8*)&Ab[frag3(wm * 64 + m * 16 + l15, kk)];
#pragma unroll
        for (int n = 0; n < 4; ++n)
            bfr[n] = *(const bf16x8*)&Bb[frag3(wn * 64 + n * 16 + l15, kk)];
        // per-lane partial row sums (P is pre-masked: zeros beyond diagonal)
#pragma unroll
        for (int m = 0; m < 4; ++m) {
            float part = 0.f;
#pragma unroll
            for (int e = 0; e < 8; ++e) part += bf2f(af[m].u[e]);
            lsum[m] += part;
        }
#pragma unroll
        for (int m = 0; m < 4; ++m)
#pragma unroll
            for (int n = 0; n < 4; ++n)
                acc[m][n] = __builtin_amdgcn_mfma_f32_16x16x32_bf16(
                    af[m].v, bfr[n], acc[m][n], 0, 0, 0);
        if (t + 1 < NT) {
            if (t + 2 < NT) VM4(); else VM0();
            SBAR();
        }
    }
    #undef STGF

    float* Ob = O + (size_t)b * 2048 * 1024 + (size_t)bm * 128 * 1024 + bn * 128;
#pragma unroll
    for (int m = 0; m < 4; ++m) {
        // full row-sum for row (wm*64 + m*16 + l15): add the 4 kk-groups
        float rs = lsum[m];
        rs += __shfl_xor(rs, 16);
        rs += __shfl_xor(rs, 32);
#pragma unroll
        for (int j2 = 0; j2 < 4; ++j2) {
            float lj = __shfl(rs, (lane >> 4) * 4 + j2);   // row ...+ (g*4+j2)
            float inv = 1.f / lj;
            int row = wm * 64 + m * 16 + (lane >> 4) * 4 + j2;
#pragma unroll
            for (int n = 0; n < 4; ++n) {
                int col = wn * 64 + n * 16 + (lane & 15);
                Ob[(size_t)row * 1024 + col] = acc[m][n][j2] * inv;
            }
        }
    }
}

// ---------------------------------------------------------------------------
// Workspace (bf16 elems), 48M total (1M = 1024*1024):
//   P    @ 0     (16M)  -- exp'd masked probabilities (unnormalized)
//     WqT @ 0 (1M), WkT @ 1M (1M), Bmat @ 2M (2M) -- dead before P
//   Xb   @ 16M  (8M)  -- alive through scores
//   T1   @ 24M  (8M)
//   V    @ 32M  (8M)
//   Vt   @ 40M  (8M)
// ---------------------------------------------------------------------------
extern "C" void kernel_launch(void* const* d_in, const int* in_sizes, int n_in,
                              void* d_out, int out_size, void* d_ws, size_t ws_size,
                              hipStream_t stream) {
    const float* x  = (const float*)d_in[0];
    const float* Wq = (const float*)d_in[1];
    const float* Wk = (const float*)d_in[2];
    const float* Wv = (const float*)d_in[3];
    float* out = (float*)d_out;
    ushort_t* ws = (ushort_t*)d_ws;
    const size_t M1 = (size_t)1024 * 1024;
    ushort_t* P    = ws;
    ushort_t* WqT  = ws;
    ushort_t* WkT  = ws + M1;
    ushort_t* Bmat = ws + 2 * M1;
    ushort_t* Xb   = ws + 16 * M1;
    ushort_t* T1   = ws + 24 * M1;
    ushort_t* V    = ws + 32 * M1;
    ushort_t* Vt   = ws + 40 * M1;

    conv_all<<<dim3(4608 + 512), 256, 0, stream>>>(x, Wq, Wk, Wv,
                                                   Xb, Bmat + M1, WqT, WkT);
    mt_gemm<<<dim3(8, 8), 256, 0, stream>>>(WkT, WqT, Bmat);
    t1v_gemm256<<<dim3(256), 1024, 0, stream>>>(Xb, Bmat, T1, V);
    scores_gemm256<<<dim3(256), 1024, 0, stream>>>(T1, Xb, P, V, Vt);
    pv_fused<<<dim3(512), 256, 0, stream>>>(P, Vt, out);
}

// Round 17
// 131.240 us; speedup vs baseline: 1.0137x; 1.0137x over previous
//
#include <hip/hip_runtime.h>
#include <hip/hip_bf16.h>

typedef unsigned int uint32;
typedef unsigned short ushort_t;

typedef __bf16 bf16x8 __attribute__((ext_vector_type(8)));
typedef float f32x4 __attribute__((ext_vector_type(4)));

__device__ __forceinline__ ushort_t f2bf(float f) {
    uint32 u = __float_as_uint(f);
    u += 0x7fffu + ((u >> 16) & 1u);
    return (ushort_t)(u >> 16);
}
__device__ __forceinline__ float bf2f(ushort_t h) {
    return __uint_as_float(((uint32)h) << 16);
}

union U16 { int4 v; ushort_t u[8]; };
union UB8 { bf16x8 v; ushort_t u[8]; };

// async global->LDS, 16B per lane (dest = wave-uniform base + lane*16)
__device__ __forceinline__ void gll16(const ushort_t* g, ushort_t* l) {
    __builtin_amdgcn_global_load_lds(
        (const __attribute__((address_space(1))) unsigned int*)g,
        (__attribute__((address_space(3))) unsigned int*)l, 16, 0, 0);
}

#define SBAR() __builtin_amdgcn_s_barrier()
#define VM0()  asm volatile("s_waitcnt vmcnt(0)" ::: "memory")
#define VM2()  asm volatile("s_waitcnt vmcnt(2)" ::: "memory")
#define VM4()  asm volatile("s_waitcnt vmcnt(4)" ::: "memory")
#define LGKM0() asm volatile("s_waitcnt lgkmcnt(0)" ::: "memory")

// swizzled LDS fragment offset (BK=32): row r, kk in {0,8,16,24}
__device__ __forceinline__ int frag3(int r, int kk) {
    return r * 32 + ((((kk >> 3) ^ ((r >> 1) & 3))) << 3);
}

// ===========================================================================
// 256x256 GEMM bf16, BK=32, 1024 thr = 16 waves, 3-ring 96KB.
// Deep prefetch: stage A,B of tile t+2 during tile t; boundary vmcnt(2).
// ===========================================================================
template<int NT>
__device__ __forceinline__ void gemm256_bk32(
    const ushort_t* __restrict__ A, int lda,
    const ushort_t* __restrict__ B, int ldb,
    ushort_t* lds, f32x4 acc[4][4])
{
    const int tid = threadIdx.x;
    const int lane = tid & 63, wid = tid >> 6;
    const int wm = wid >> 2, wn = wid & 3;
    const int l15 = lane & 15, kk = (lane >> 4) * 8;
    const int srow = tid >> 2;
    const int sc4 = (tid & 3) ^ ((tid >> 3) & 3);   // inverse swizzle on src

    #define STAGE3(G, ldg, X, op)                                            \
        gll16(&(G)[(size_t)srow * (ldg) + (X) * 32 + sc4 * 8],               \
              &lds[(((X) % 3) * 2 + (op)) * 8192 + tid * 8])

    STAGE3(A, lda, 0, 0);
    STAGE3(B, ldb, 0, 1);
    if (NT > 1) { STAGE3(A, lda, 1, 0); STAGE3(B, ldb, 1, 1); VM2(); }
    else VM0();
    SBAR();

    for (int t = 0; t < NT; ++t) {
        const ushort_t* Ab = lds + (t % 3) * 16384;
        const ushort_t* Bb = Ab + 8192;
        if (t + 2 < NT) { STAGE3(A, lda, t + 2, 0); STAGE3(B, ldb, t + 2, 1); }
        bf16x8 af[4], bfr[4];
#pragma unroll
        for (int m = 0; m < 4; ++m)
            af[m] = *(const bf16x8*)&Ab[frag3(wm * 64 + m * 16 + l15, kk)];
#pragma unroll
        for (int n = 0; n < 4; ++n)
            bfr[n] = *(const bf16x8*)&Bb[frag3(wn * 64 + n * 16 + l15, kk)];
#pragma unroll
        for (int m = 0; m < 4; ++m)
#pragma unroll
            for (int n = 0; n < 4; ++n)
                acc[m][n] = __builtin_amdgcn_mfma_f32_16x16x32_bf16(
                    af[m], bfr[n], acc[m][n], 0, 0, 0);
        if (t + 1 < NT) {
            if (t + 2 < NT) VM2(); else VM0();
            SBAR();
        }
    }
    #undef STAGE3
}

// ===========================================================================
// 128x128 GEMM bf16, BK=32, 256 thr = 4 waves, RING-4 (64KB, 2 blocks/CU).
// Stage A,B of t+2 during t; boundary vmcnt(4).
// ===========================================================================
__device__ __forceinline__ void gemm128_bk32(
    const ushort_t* __restrict__ A, int lda,
    const ushort_t* __restrict__ B, int ldb,
    ushort_t* lds, int NT, f32x4 acc[4][4])
{
    const int tid = threadIdx.x;
    const int lane = tid & 63, wid = tid >> 6;
    const int wm = wid >> 1, wn = wid & 1;
    const int l15 = lane & 15, kk = (lane >> 4) * 8;

    #define STG128(G, ldg, X, op) do {                                       \
        _Pragma("unroll")                                                    \
        for (int i = 0; i < 2; ++i) {                                        \
            int c = i * 256 + tid;                                           \
            int row = c >> 2;                                                \
            int slot = (c & 3) ^ ((row >> 1) & 3);                           \
            gll16(&(G)[(size_t)row * (ldg) + (X) * 32 + slot * 8],           \
                  &lds[(((X) % 4) * 2 + (op)) * 4096 + c * 8]);              \
        } } while (0)

    STG128(A, lda, 0, 0);
    STG128(B, ldb, 0, 1);
    if (NT > 1) { STG128(A, lda, 1, 0); STG128(B, ldb, 1, 1); VM4(); }
    else VM0();
    SBAR();

    for (int t = 0; t < NT; ++t) {
        const ushort_t* Ab = lds + (t % 4) * 8192;
        const ushort_t* Bb = Ab + 4096;
        if (t + 2 < NT) { STG128(A, lda, t + 2, 0); STG128(B, ldb, t + 2, 1); }
        bf16x8 af[4], bfr[4];
#pragma unroll
        for (int m = 0; m < 4; ++m)
            af[m] = *(const bf16x8*)&Ab[frag3(wm * 64 + m * 16 + l15, kk)];
#pragma unroll
        for (int n = 0; n < 4; ++n)
            bfr[n] = *(const bf16x8*)&Bb[frag3(wn * 64 + n * 16 + l15, kk)];
#pragma unroll
        for (int m = 0; m < 4; ++m)
#pragma unroll
            for (int n = 0; n < 4; ++n)
                acc[m][n] = __builtin_amdgcn_mfma_f32_16x16x32_bf16(
                    af[m], bfr[n], acc[m][n], 0, 0, 0);
        if (t + 1 < NT) {
            if (t + 2 < NT) VM4(); else VM0();
            SBAR();
        }
    }
    #undef STG128
}

// ---------------------------------------------------------------------------
// Kernel 0 (merged): fp32->bf16 copies (X, Wv->Bmat rows 1024..2047) +
// transpose-convert Wq,Wk -> WqT,WkT.
// ---------------------------------------------------------------------------
__global__ __launch_bounds__(256) void conv_all(
    const float* __restrict__ X,  const float* __restrict__ Wq,
    const float* __restrict__ Wk, const float* __restrict__ Wv,
    ushort_t* __restrict__ Xb, ushort_t* __restrict__ BmatV,
    ushort_t* __restrict__ WqT, ushort_t* __restrict__ WkT)
{
    __shared__ ushort_t ts[64][72];
    const int gb = blockIdx.x;
    const int tid = threadIdx.x;
    if (gb < 4608) {
        const float* src;
        ushort_t* dst;
        if (gb < 4096) {
            size_t base = ((size_t)gb * 256 + tid) * 8;
            src = X + base; dst = Xb + base;
        } else {
            size_t base = ((size_t)(gb - 4096) * 256 + tid) * 8;
            src = Wv + base; dst = BmatV + base;
        }
        float4 f0 = *(const float4*)src;
        float4 f1 = *(const float4*)(src + 4);
        U16 o;
        o.u[0] = f2bf(f0.x); o.u[1] = f2bf(f0.y); o.u[2] = f2bf(f0.z); o.u[3] = f2bf(f0.w);
        o.u[4] = f2bf(f1.x); o.u[5] = f2bf(f1.y); o.u[6] = f2bf(f1.z); o.u[7] = f2bf(f1.w);
        *(int4*)dst = o.v;
        return;
    }
    // ---- transpose path
    const int t2 = gb - 4608;            // [0,512)
    const int z = t2 >> 8;
    const int bx = t2 & 15, by = (t2 >> 4) & 15;
    const float* W = z ? Wk : Wq;
    ushort_t* Dt = z ? WkT : WqT;
    const int o0 = bx * 64, d0 = by * 64;
    const int row = tid >> 2, q = tid & 3;
#pragma unroll
    for (int c4 = 0; c4 < 4; ++c4) {
        float4 f = *(const float4*)&W[(size_t)(o0 + row) * 1024 + d0 + q * 16 + c4 * 4];
        ts[row][q * 16 + c4 * 4 + 0] = f2bf(f.x);
        ts[row][q * 16 + c4 * 4 + 1] = f2bf(f.y);
        ts[row][q * 16 + c4 * 4 + 2] = f2bf(f.z);
        ts[row][q * 16 + c4 * 4 + 3] = f2bf(f.w);
    }
    __syncthreads();
#pragma unroll
    for (int i = 0; i < 2; ++i) {
        int c = tid + 256 * i;
        int drow = c >> 3, ocol8 = c & 7;
        U16 vv;
#pragma unroll
        for (int j = 0; j < 8; ++j) vv.u[j] = ts[ocol8 * 8 + j][drow];
        *(int4*)&Dt[(size_t)(d0 + drow) * 1024 + o0 + ocol8 * 8] = vv.v;
    }
}

// ---------------------------------------------------------------------------
// Kernel 0c: Mt GEMM: Bmat[a][d] = sum_o WkT[a][o]*WqT[d][o]. grid (8,8).
// ---------------------------------------------------------------------------
__global__ __launch_bounds__(256) void mt_gemm(
    const ushort_t* __restrict__ WkT, const ushort_t* __restrict__ WqT,
    ushort_t* __restrict__ Bmat)
{
    __shared__ __align__(16) ushort_t lds[32768];  // 64 KB (ring-4)
    const int bm = blockIdx.y, bn = blockIdx.x;
    const int tid = threadIdx.x;
    f32x4 acc[4][4] = {};
    gemm128_bk32(WkT + (size_t)bm * 128 * 1024, 1024,
                 WqT + (size_t)bn * 128 * 1024, 1024, lds, 32, acc);
    ushort_t* Dst = Bmat + (size_t)bm * 128 * 1024 + bn * 128;
    const int lane = tid & 63, wid = tid >> 6;
    const int wr = wid >> 1, wc = wid & 1;
#pragma unroll
    for (int m = 0; m < 4; ++m)
#pragma unroll
        for (int n = 0; n < 4; ++n)
#pragma unroll
            for (int j = 0; j < 4; ++j) {
                int row = wr * 64 + m * 16 + (lane >> 4) * 4 + j;
                int col = wc * 64 + n * 16 + (lane & 15);
                Dst[(size_t)row * 1024 + col] = f2bf(acc[m][n][j]);
            }
}

// ---------------------------------------------------------------------------
// Kernel 1: T1|V projection. 1-D grid 256, XCD-swizzled. 1024 thr.
// Epilogue: per-wave LDS repack -> coalesced int4 stores (8 VMEM/thread
// instead of 64 scalar bf16 stores). Patch stride 72 ushorts (bank-spread);
// wave-private, DS in-order => no barriers inside repack.
// ---------------------------------------------------------------------------
__global__ __launch_bounds__(1024) void t1v_gemm256(
    const ushort_t* __restrict__ Xb, const ushort_t* __restrict__ Bmat,
    ushort_t* __restrict__ T1, ushort_t* __restrict__ V)
{
    __shared__ __align__(16) ushort_t lds[49152];  // 96 KB
    const int id = blockIdx.x;            // [0,256)
    const int xcd = id & 7, l = id >> 3;  // l in [0,32)
    const int bm = xcd * 4 + (l >> 3);    // [0,32)
    const int bn = l & 7;                 // [0,8)
    f32x4 acc[4][4] = {};
    gemm256_bk32<32>(Xb + (size_t)bm * 256 * 1024, 1024,
                     Bmat + (size_t)bn * 256 * 1024, 1024, lds, acc);
    __syncthreads();   // patches alias ring buffers other waves still read
    ushort_t* Dst = ((bn < 4) ? T1 : V)
                  + (size_t)bm * 256 * 1024 + (bn & 3) * 256;
    const int tid = threadIdx.x, lane = tid & 63, wid = tid >> 6;
    const int wm = wid >> 2, wn = wid & 3;
    const int l15 = lane & 15, g = lane >> 4;
    ushort_t* patch = lds + wid * 2304;   // 32 rows x 72 = 2304 ushorts
#pragma unroll
    for (int h = 0; h < 2; ++h) {
#pragma unroll
        for (int mm = 0; mm < 2; ++mm) {
            int m = 2 * h + mm;
#pragma unroll
            for (int n = 0; n < 4; ++n)
#pragma unroll
                for (int j = 0; j < 4; ++j)
                    patch[(mm * 16 + g * 4 + j) * 72 + n * 16 + l15] =
                        f2bf(acc[m][n][j]);
        }
        LGKM0();
#pragma unroll
        for (int i = 0; i < 4; ++i) {
            int idx = i * 64 + lane;
            int lrow = idx >> 3, chunk = idx & 7;
            int4 v = *(const int4*)&patch[lrow * 72 + chunk * 8];
            int grow = wm * 64 + h * 32 + lrow;
            int gcol = wn * 64 + chunk * 8;
            *(int4*)&Dst[(size_t)grow * 1024 + gcol] = v;
        }
        LGKM0();   // reads retired before next half overwrites patch
    }
}

// ---------------------------------------------------------------------------
// Kernel 2: P = exp((T1 @ X^T)/32) bf16, causal-masked (exact 0), 256^2;
// masked blocks transpose V. 1-D grid 256, XCD-swizzled.
// Epilogue repacked like t1v (exp+mask applied in-register before LDS).
// ---------------------------------------------------------------------------
__global__ __launch_bounds__(1024) void scores_gemm256(
    const ushort_t* __restrict__ T1, const ushort_t* __restrict__ Xb,
    ushort_t* __restrict__ P,
    const ushort_t* __restrict__ V, ushort_t* __restrict__ Vt)
{
    __shared__ __align__(16) ushort_t lds[49152];
    const int id = blockIdx.x;            // [0,256)
    const int xcd = id & 7, l = id >> 3;  // l in [0,32)
    const int b = xcd >> 1, h2 = xcd & 1;
    const int bm = 4 * h2 + (l >> 3);     // [0,8)
    const int bn = l & 7;                 // [0,8)
    const int tid = threadIdx.x;
    if (bn > bm) {
        // ---- V-transpose duty: 512 64x64 tiles/batch over 28 masked blocks
        ushort_t (*ts)[72] = (ushort_t(*)[72])lds;
        const ushort_t* Vb = V + (size_t)b * 2048 * 1024;
        ushort_t* Vtb = Vt + (size_t)b * 1024 * 2048;
        const int rank = bn * (bn - 1) / 2 + bm;   // [0,28)
        for (int t = rank; t < 512; t += 28) {
            int k0 = (t >> 4) * 64, d0 = (t & 15) * 64;
            __syncthreads();
            if (tid < 512) {
                int row = tid >> 3, col8 = tid & 7;
                U16 vv;
                vv.v = *(const int4*)&Vb[(size_t)(k0 + row) * 1024 + d0 + col8 * 8];
#pragma unroll
                for (int j = 0; j < 8; ++j) ts[row][col8 * 8 + j] = vv.u[j];
            }
            __syncthreads();
            if (tid < 512) {
                int drow = tid >> 3, kcol8 = tid & 7;
                U16 vv;
#pragma unroll
                for (int j = 0; j < 8; ++j) vv.u[j] = ts[kcol8 * 8 + j][drow];
                *(int4*)&Vtb[(size_t)(d0 + drow) * 2048 + k0 + kcol8 * 8] = vv.v;
            }
        }
        return;
    }
    f32x4 acc[4][4] = {};
    gemm256_bk32<32>(T1 + (size_t)b * 2048 * 1024 + (size_t)bm * 256 * 1024, 1024,
                     Xb + (size_t)b * 2048 * 1024 + (size_t)bn * 256 * 1024, 1024,
                     lds, acc);
    __syncthreads();
    ushort_t* Pb = P + (size_t)b * 2048 * 2048 + (size_t)bm * 256 * 2048 + bn * 256;
    const int lane = tid & 63, wid = tid >> 6;
    const int wm = wid >> 2, wn = wid & 3;
    const int l15 = lane & 15, g = lane >> 4;
    const bool diag = (bn == bm);
    ushort_t* patch = lds + wid * 2304;
#pragma unroll
    for (int h = 0; h < 2; ++h) {
#pragma unroll
        for (int mm = 0; mm < 2; ++mm) {
            int m = 2 * h + mm;
#pragma unroll
            for (int n = 0; n < 4; ++n)
#pragma unroll
                for (int j = 0; j < 4; ++j) {
                    int lrow = mm * 16 + g * 4 + j;
                    int lcol = n * 16 + l15;
                    float p = __expf(fminf(acc[m][n][j] * 0.03125f, 30.f));
                    if (diag) {
                        int row = wm * 64 + h * 32 + lrow;   // within 256-tile
                        int col = wn * 64 + lcol;
                        if (col > row) p = 0.f;              // causal: exact 0
                    }
                    patch[lrow * 72 + lcol] = f2bf(p);
                }
        }
        LGKM0();
#pragma unroll
        for (int i = 0; i < 4; ++i) {
            int idx = i * 64 + lane;
            int lrow = idx >> 3, chunk = idx & 7;
            int4 v = *(const int4*)&patch[lrow * 72 + chunk * 8];
            int grow = wm * 64 + h * 32 + lrow;
            int gcol = wn * 64 + chunk * 8;
            *(int4*)&Pb[(size_t)grow * 2048 + gcol] = v;
        }
        LGKM0();
    }
}

// ---------------------------------------------------------------------------
// Kernel 3: pv_fused = P@V + rowsum normalize (P pre-exp'd, pre-masked).
// RING-4 deep prefetch. Mapping: R15 complementary per-XCD balance
// (R16's XCD-grouping was neutral -> reverted). f32 stores are 64B-segment
// coalesced, left direct.
// ---------------------------------------------------------------------------
__global__ __launch_bounds__(256) void pv_fused(
    const ushort_t* __restrict__ S, const ushort_t* __restrict__ Vt,
    float* __restrict__ O)
{
    __shared__ __align__(16) ushort_t lds[32768];  // 64 KB (ring-4)
    const int L = blockIdx.x;   // [0,512)
    int b, bm, bn;
    if (L < 256) {
        int c = L >> 4;
        b = c >> 3; bn = c & 7; bm = 15 - (L & 15);
    } else {
        int L2 = L - 256;
        int c = L2 >> 4;
        b = 2 + (c >> 3); bn = c & 7; bm = L2 & 15;
    }
    const int tid = threadIdx.x;
    const int lane = tid & 63, wid = tid >> 6;
    const int wm = wid >> 1, wn = wid & 1;
    const int l15 = lane & 15, kk = (lane >> 4) * 8;
    const ushort_t* A = S + (size_t)b * 2048 * 2048 + (size_t)bm * 128 * 2048;
    const ushort_t* Bm = Vt + (size_t)b * 1024 * 2048 + (size_t)bn * 128 * 2048;
    const int NT = (bm + 1) * 4;

    f32x4 acc[4][4] = {};
    float lsum[4] = {0.f, 0.f, 0.f, 0.f};

    #define STGF(G, ldg, X, op) do {                                         \
        _Pragma("unroll")                                                    \
        for (int i = 0; i < 2; ++i) {                                        \
            int c = i * 256 + tid;                                           \
            int row = c >> 2;                                                \
            int slot = (c & 3) ^ ((row >> 1) & 3);                           \
            gll16(&(G)[(size_t)row * (ldg) + (X) * 32 + slot * 8],           \
                  &lds[(((X) % 4) * 2 + (op)) * 4096 + c * 8]);              \
        } } while (0)

    STGF(A, 2048, 0, 0);
    STGF(Bm, 2048, 0, 1);
    if (NT > 1) { STGF(A, 2048, 1, 0); STGF(Bm, 2048, 1, 1); VM4(); }
    else VM0();
    SBAR();

    for (int t = 0; t < NT; ++t) {
        const ushort_t* Ab = lds + (t % 4) * 8192;
        const ushort_t* Bb = Ab + 4096;
        if (t + 2 < NT) { STGF(A, 2048, t + 2, 0); STGF(Bm, 2048, t + 2, 1); }
        UB8 af[4];
        bf16x8 bfr[4];
#pragma unroll
        for (int m = 0; m < 4; ++m)
            af[m].v = *(const bf16x8*)&Ab[frag3(wm * 64 + m * 16 + l15, kk)];
#pragma unroll
        for (int n = 0; n < 4; ++n)
            bfr[n] = *(const bf16x8*)&Bb[frag3(wn * 64 + n * 16 + l15, kk)];
        // per-lane partial row sums (P is pre-masked: zeros beyond diagonal)
#pragma unroll
        for (int m = 0; m < 4; ++m) {
            float part = 0.f;
#pragma unroll
            for (int e = 0; e < 8; ++e) part += bf2f(af[m].u[e]);
            lsum[m] += part;
        }
#pragma unroll
        for (int m = 0; m < 4; ++m)
#pragma unroll
            for (int n = 0; n < 4; ++n)
                acc[m][n] = __builtin_amdgcn_mfma_f32_16x16x32_bf16(
                    af[m].v, bfr[n], acc[m][n], 0, 0, 0);
        if (t + 1 < NT) {
            if (t + 2 < NT) VM4(); else VM0();
            SBAR();
        }
    }
    #undef STGF

    float* Ob = O + (size_t)b * 2048 * 1024 + (size_t)bm * 128 * 1024 + bn * 128;
#pragma unroll
    for (int m = 0; m < 4; ++m) {
        // full row-sum for row (wm*64 + m*16 + l15): add the 4 kk-groups
        float rs = lsum[m];
        rs += __shfl_xor(rs, 16);
        rs += __shfl_xor(rs, 32);
#pragma unroll
        for (int j2 = 0; j2 < 4; ++j2) {
            float lj = __shfl(rs, (lane >> 4) * 4 + j2);   // row ...+ (g*4+j2)
            float inv = 1.f / lj;
            int row = wm * 64 + m * 16 + (lane >> 4) * 4 + j2;
#pragma unroll
            for (int n = 0; n < 4; ++n) {
                int col = wn * 64 + n * 16 + (lane & 15);
                Ob[(size_t)row * 1024 + col] = acc[m][n][j2] * inv;
            }
        }
    }
}

// ---------------------------------------------------------------------------
// Workspace (bf16 elems), 48M total (1M = 1024*1024):
//   P    @ 0     (16M)  -- exp'd masked probabilities (unnormalized)
//     WqT @ 0 (1M), WkT @ 1M (1M), Bmat @ 2M (2M) -- dead before P
//   Xb   @ 16M  (8M)  -- alive through scores
//   T1   @ 24M  (8M)
//   V    @ 32M  (8M)
//   Vt   @ 40M  (8M)
// ---------------------------------------------------------------------------
extern "C" void kernel_launch(void* const* d_in, const int* in_sizes, int n_in,
                              void* d_out, int out_size, void* d_ws, size_t ws_size,
                              hipStream_t stream) {
    const float* x  = (const float*)d_in[0];
    const float* Wq = (const float*)d_in[1];
    const float* Wk = (const float*)d_in[2];
    const float* Wv = (const float*)d_in[3];
    float* out = (float*)d_out;
    ushort_t* ws = (ushort_t*)d_ws;
    const size_t M1 = (size_t)1024 * 1024;
    ushort_t* P    = ws;
    ushort_t* WqT  = ws;
    ushort_t* WkT  = ws + M1;
    ushort_t* Bmat = ws + 2 * M1;
    ushort_t* Xb   = ws + 16 * M1;
    ushort_t* T1   = ws + 24 * M1;
    ushort_t* V    = ws + 32 * M1;
    ushort_t* Vt   = ws + 40 * M1;

    conv_all<<<dim3(4608 + 512), 256, 0, stream>>>(x, Wq, Wk, Wv,
                                                   Xb, Bmat + M1, WqT, WkT);
    mt_gemm<<<dim3(8, 8), 256, 0, stream>>>(WkT, WqT, Bmat);
    t1v_gemm256<<<dim3(256), 1024, 0, stream>>>(Xb, Bmat, T1, V);
    scores_gemm256<<<dim3(256), 1024, 0, stream>>>(T1, Xb, P, V, Vt);
    pv_fused<<<dim3(512), 256, 0, stream>>>(P, Vt, out);
}